// Round 8
// baseline (596.731 us; speedup 1.0000x reference)
//
#include <hip/hip_runtime.h>
#include <cmath>

// ---------- constants ----------
#define IMG 131072        // 512*256 per batch image
#define BIGF 1048576      // 8*512*256
#define SBIG 1048576      // elements per split plane (8*IMG)
#define MB (1u<<20)
#define TS (4u*MB)        // bytes per tensor (split: 2 planes x 2MB; fp32: 4MB)

// pool layout (bytes); each section = 2 branches x TS
#define OFF_W   0u          // 8 weight mats x 1MB (hi 512K shorts + lo)
#define OFF_UP  (8u*MB)
#define OFF_SAS (16u*MB)
#define OFF_AP  (24u*MB)
#define OFF_CA  (32u*MB)
#define OFF_PQ  (40u*MB)
#define OFF_PK  (48u*MB)
#define OFF_PV  (56u*MB)
#define OFF_OS  (64u*MB)
#define OFF_LN  (72u*MB)
#define OFF_FSA (80u*MB)
#define OFF_FV  (88u*MB)
#define OFF_FO  (96u*MB)

__device__ __attribute__((aligned(256))) unsigned char g_pool[104u*MB];

__device__ __forceinline__ unsigned short* SPL(size_t off){ return (unsigned short*)(g_pool + off); }
__device__ __forceinline__ float* F32(size_t off){ return (float*)(g_pool + off); }

#define CF_RELU  1
#define CF_BN    2
#define CF_RESE  4
#define CF_RESP  8
#define CF_OF32E 16
#define CF_OF32P 32
#define CF_OSPL  64

typedef __attribute__((ext_vector_type(8))) short short8;
typedef __attribute__((ext_vector_type(4))) short short4v;
typedef __attribute__((ext_vector_type(4))) unsigned short ushort4v;
typedef __attribute__((ext_vector_type(4))) float f32x4;

__device__ __forceinline__ float wave_sum(float v){
    #pragma unroll
    for (int off = 32; off; off >>= 1) v += __shfl_xor(v, off);
    return v;
}
__device__ __forceinline__ unsigned short bf16_rn(float x){
    union { float f; unsigned u; } v; v.f = x;
    unsigned r = v.u + 0x7FFF + ((v.u >> 16) & 1);
    return (unsigned short)(r >> 16);
}
__device__ __forceinline__ float bf16_to_f(unsigned short h){
    union { float f; unsigned u; } v; v.u = ((unsigned)h) << 16;
    return v.f;
}

// ---------- job structs ----------
struct GapJobs  { const float* x[2]; size_t off[2]; float* o[2]; };
struct G8Job    { const float* in; const float* W; const float* bias; const float* add; float* out; };
struct G8Jobs   { G8Job j[4]; };
struct AAJobs   { const float* qkv[2]; float* om[2]; };
struct LnJobs   { const float* in[2]; float* out[2]; };
struct UpJobs   { const float* in[2]; };
struct SAJobs   { const float* q8[2]; const float* k8[2]; float* aw[2]; };
struct SPJobs   { const float* aw[2]; };
struct W8       { const float* w[8]; };
struct ConvJob  { size_t xoff, ooff, osoff, roff; const float* Rext; float* OextW;
                  const float* Bp; int widx, flags; };
struct ConvJobs { ConvJob j[6]; };
struct PixLnJobs{ const float* in[2]; };

// ---------- weight pre-split: 8 matrices -> hi/lo bf16 planes ----------
__global__ __launch_bounds__(256) void k_splitw(W8 ws){
    const int m = blockIdx.y;
    const int i = (blockIdx.x*256 + threadIdx.x)*4;   // 262144 el -> grid.x=256
    float4 v = *(const float4*)(ws.w[m] + i);
    unsigned short* WH = (unsigned short*)(g_pool + (size_t)m*1048576u);
    unsigned short* WL = WH + 262144;
    float vv[4] = {v.x, v.y, v.z, v.w};
    ushort4v hi, lo;
    #pragma unroll
    for (int j = 0; j < 4; j++){
        hi[j] = bf16_rn(vv[j]);
        lo[j] = bf16_rn(vv[j] - bf16_to_f(hi[j]));
    }
    *(ushort4v*)&WH[i] = hi;
    *(ushort4v*)&WL[i] = lo;
}

// ---------- fp32 -> split (pixel O) ----------
__global__ __launch_bounds__(256) void k_split_o(){
    const int br = blockIdx.y;
    const int i = (blockIdx.x*256 + threadIdx.x)*4;   // SBIG/4/256 = 1024 blocks
    const float* src = F32(OFF_FO + (size_t)br*TS);
    unsigned short* H = SPL(OFF_OS + (size_t)br*TS);
    float4 v = *(const float4*)(src + i);
    float vv[4] = {v.x, v.y, v.z, v.w};
    ushort4v hi, lo;
    #pragma unroll
    for (int j = 0; j < 4; j++){
        hi[j] = bf16_rn(vv[j]);
        lo[j] = bf16_rn(vv[j] - bf16_to_f(hi[j]));
    }
    *(ushort4v*)&H[i] = hi;
    *(ushort4v*)&H[SBIG + i] = lo;
}

// ---------- zero pixel O accumulators ----------
__global__ __launch_bounds__(256) void k_zero(){
    float* p = F32(OFF_FO + (size_t)blockIdx.y*TS);
    const int i = (blockIdx.x*256 + threadIdx.x)*4;
    *(float4*)&p[i] = make_float4(0.f,0.f,0.f,0.f);
}

// ---------- GAP ----------
__global__ __launch_bounds__(64) void k_gap(GapJobs jo){
    const int br = blockIdx.y;
    const int bc = blockIdx.x;
    const int lane = threadIdx.x;
    const float* base = jo.x[br] ? jo.x[br] : F32(jo.off[br]);
    const float* p = base + (size_t)bc * 256;
    float s = p[lane] + p[lane + 64] + p[lane + 128] + p[lane + 192];
    s = wave_sum(s);
    if (lane == 0) jo.o[br][bc] = s * (1.0f / 256.0f);
}

// ---------- tiny GEMM ----------
__global__ __launch_bounds__(64) void k_gemm8(G8Jobs jo, int add_off, int add_stride, int O, int relu){
    const G8Job j = jo.j[blockIdx.y];
    const int o = blockIdx.x;
    const int lane = threadIdx.x;
    const float* wr = j.W + (size_t)o * 512;
    float acc[8] = {0,0,0,0,0,0,0,0};
    #pragma unroll
    for (int i = 0; i < 8; i++){
        float w = wr[lane + 64*i];
        #pragma unroll
        for (int b = 0; b < 8; b++) acc[b] += w * j.in[b*512 + lane + 64*i];
    }
    #pragma unroll
    for (int b = 0; b < 8; b++) acc[b] = wave_sum(acc[b]);
    if (lane < 8){
        float v = acc[0];
        #pragma unroll
        for (int b = 1; b < 8; b++) if (lane == b) v = acc[b];
        v += j.bias[o];
        if (j.add) v += j.add[lane*add_stride + add_off + o];
        if (relu) v = fmaxf(v, 0.f);
        j.out[(size_t)lane * O + o] = v;
    }
}

// ---------- asri batch-axis attention ----------
__global__ __launch_bounds__(64) void k_asri_attn(AAJobs jo){
    const int br = blockIdx.y;
    const float* qkv = jo.qkv[br];
    const int h = blockIdx.x >> 3, b = blockIdx.x & 7, c = threadIdx.x;
    const int ci = c*8 + h;
    float qc = qkv[b*2048 + ci];
    float s[8];
    #pragma unroll
    for (int d = 0; d < 8; d++){
        float p = qc * qkv[d*2048 + 512 + ci];
        p = wave_sum(p);
        s[d] = p * 0.125f;
    }
    float m = s[0];
    #pragma unroll
    for (int d = 1; d < 8; d++) m = fmaxf(m, s[d]);
    float sum = 0.f;
    #pragma unroll
    for (int d = 0; d < 8; d++){ s[d] = __expf(s[d]-m); sum += s[d]; }
    float r = 1.f / sum;
    float oc = 0.f;
    #pragma unroll
    for (int d = 0; d < 8; d++) oc += s[d]*r * qkv[d*2048 + 1024 + ci];
    jo.om[br][b*512 + ci] = oc;
}

// ---------- LN over 512, 8 rows ----------
__global__ __launch_bounds__(64) void k_ln8(LnJobs jo,
    const float* __restrict__ g, const float* __restrict__ be)
{
    const int br = blockIdx.y;
    const int b = blockIdx.x, lane = threadIdx.x;
    const float* in = jo.in[br];
    float v[8]; float s = 0.f;
    #pragma unroll
    for (int i = 0; i < 8; i++){ v[i] = in[b*512 + lane + 64*i]; s += v[i]; }
    s = wave_sum(s);
    float mean = s * (1.f/512.f);
    float q = 0.f;
    #pragma unroll
    for (int i = 0; i < 8; i++){ float d = v[i]-mean; q += d*d; }
    q = wave_sum(q);
    float rstd = rsqrtf(q*(1.f/512.f) + 1e-5f);
    #pragma unroll
    for (int i = 0; i < 8; i++){
        int c = lane + 64*i;
        jo.out[br][b*512 + c] = (v[i]-mean)*rstd*g[c] + be[c];
    }
}

// ---------- bilinear upsample -> split output (feeds c2 conv only) ----------
__global__ __launch_bounds__(256) void k_up(UpJobs jo){
    const int br = blockIdx.y;
    const int idx = blockIdx.x*256 + threadIdx.x;
    const int x = idx & 15, y = (idx >> 4) & 15, bc = idx >> 8;
    float px = (float)(x*3) / 15.0f, py = (float)(y*3) / 15.0f;
    int lx = (int)px, ly = (int)py;
    float wx = px - lx, wy = py - ly;
    int hx = min(lx+1, 3), hy = min(ly+1, 3);
    const float* p = jo.in[br] + (size_t)bc * 16;
    float v00 = p[ly*4+lx], v01 = p[ly*4+hx], v10 = p[hy*4+lx], v11 = p[hy*4+hx];
    float a0 = v00*(1.f-wy) + v10*wy;
    float a1 = v01*(1.f-wy) + v11*wy;
    float val = a0*(1.f-wx) + a1*wx;
    unsigned short* H = SPL(OFF_UP + (size_t)br*TS);
    unsigned short hi = bf16_rn(val);
    H[idx] = hi;
    H[SBIG + idx] = bf16_rn(val - bf16_to_f(hi));
}

// ---------- conv1x1 split-bf16 MFMA v4: pre-split W & X, pure-copy staging ----------
// 512 thr = 2 K-groups x 4 waves; tile 64o x 64n; LDS reduction of group 1 into 0.
#define LDK 40
__global__ __launch_bounds__(512) void k_convm(ConvJobs jo,
    const float* __restrict__ bng, const float* __restrict__ bnb, float bninv)
{
    __shared__ unsigned short lds[20480];
    const int z = blockIdx.z;
    const ConvJob j = jo.j[z >> 3];
    const int b = z & 7;
    const int o0 = blockIdx.y*64, n0 = blockIdx.x*64;

    const int tid512 = threadIdx.x;
    const int g   = tid512 >> 8;
    const int tid = tid512 & 255;
    unsigned short* sAh = lds + g*10240;
    unsigned short* sAl = sAh + 2560;
    unsigned short* sBh = sAl + 2560;
    unsigned short* sBl = sBh + 2560;
    const int wv = tid >> 6, lane = tid & 63;
    const int quad = lane >> 4, l16 = lane & 15;
    const int wo = (wv >> 1) * 32, wn = (wv & 1) * 32;
    const int so  = tid >> 2, sk8 = (tid & 3) * 8;
    const int sp  = tid & 15, sn  = (tid >> 4) * 4;

    const unsigned short* WB = (const unsigned short*)(g_pool + (size_t)j.widx*1048576u);
    const unsigned short* wrowH = WB + (size_t)(o0 + so)*512 + g*256 + sk8;
    const unsigned short* wrowL = wrowH + 262144;
    const unsigned short* XB = SPL(j.xoff) + (size_t)b*IMG;
    const unsigned short* xrowH = XB + (size_t)(g*256 + 2*sp)*256 + n0 + sn;
    const unsigned short* xrowL = xrowH + SBIG;

    f32x4 acc[2][2] = {};
    short8   wh  = *(const short8*)wrowH;
    short8   wl  = *(const short8*)wrowL;
    ushort4v xh0 = *(const ushort4v*)(xrowH);
    ushort4v xh1 = *(const ushort4v*)(xrowH + 256);
    ushort4v xl0 = *(const ushort4v*)(xrowL);
    ushort4v xl1 = *(const ushort4v*)(xrowL + 256);

    for (int k0 = 0; k0 < 256; k0 += 32){
        __syncthreads();
        *(short8*)&sAh[so*LDK + sk8] = wh;
        *(short8*)&sAl[so*LDK + sk8] = wl;
        #pragma unroll
        for (int t = 0; t < 4; t++){
            *(unsigned*)&sBh[(sn+t)*LDK + 2*sp] =
                (unsigned)(unsigned short)xh0[t] | ((unsigned)(unsigned short)xh1[t] << 16);
            *(unsigned*)&sBl[(sn+t)*LDK + 2*sp] =
                (unsigned)(unsigned short)xl0[t] | ((unsigned)(unsigned short)xl1[t] << 16);
        }
        __syncthreads();
        if (k0 + 32 < 256){
            wh  = *(const short8*)(wrowH + k0 + 32);
            wl  = *(const short8*)(wrowL + k0 + 32);
            xh0 = *(const ushort4v*)(xrowH + (size_t)(k0+32)*256);
            xh1 = *(const ushort4v*)(xrowH + (size_t)(k0+32)*256 + 256);
            xl0 = *(const ushort4v*)(xrowL + (size_t)(k0+32)*256);
            xl1 = *(const ushort4v*)(xrowL + (size_t)(k0+32)*256 + 256);
        }
        short8 ah[2], al[2], bh[2], bl[2];
        #pragma unroll
        for (int t = 0; t < 2; t++){
            int ai = (wo + 16*t + l16)*LDK + quad*8;
            ah[t] = *(const short8*)&sAh[ai];
            al[t] = *(const short8*)&sAl[ai];
            int bi = (wn + 16*t + l16)*LDK + quad*8;
            bh[t] = *(const short8*)&sBh[bi];
            bl[t] = *(const short8*)&sBl[bi];
        }
        #pragma unroll
        for (int mt = 0; mt < 2; mt++){
            #pragma unroll
            for (int nt = 0; nt < 2; nt++){
                acc[mt][nt] = __builtin_amdgcn_mfma_f32_16x16x32_bf16(ah[mt], bh[nt], acc[mt][nt], 0, 0, 0);
                acc[mt][nt] = __builtin_amdgcn_mfma_f32_16x16x32_bf16(ah[mt], bl[nt], acc[mt][nt], 0, 0, 0);
                acc[mt][nt] = __builtin_amdgcn_mfma_f32_16x16x32_bf16(al[mt], bh[nt], acc[mt][nt], 0, 0, 0);
            }
        }
    }
    __syncthreads();
    float* red = (float*)lds;
    if (g == 1){
        float* r = red + tid*20;
        #pragma unroll
        for (int mt = 0; mt < 2; mt++)
            #pragma unroll
            for (int nt = 0; nt < 2; nt++)
                *(f32x4*)(r + (mt*2+nt)*4) = acc[mt][nt];
    }
    __syncthreads();
    if (g == 0){
        float* r = red + tid*20;
        #pragma unroll
        for (int mt = 0; mt < 2; mt++)
            #pragma unroll
            for (int nt = 0; nt < 2; nt++)
                acc[mt][nt] += *(const f32x4*)(r + (mt*2+nt)*4);

        const int flags = j.flags;
        const float* resb = nullptr;
        if (flags & CF_RESE) resb = j.Rext + (size_t)b*IMG;
        if (flags & CF_RESP) resb = F32(j.roff) + (size_t)b*IMG;
        float* of32 = nullptr;
        if (flags & CF_OF32E) of32 = j.OextW + (size_t)b*IMG;
        if (flags & CF_OF32P) of32 = F32(j.ooff) + (size_t)b*IMG;
        unsigned short* osH = (flags & CF_OSPL) ? SPL(j.osoff) + (size_t)b*IMG : nullptr;

        #pragma unroll
        for (int mt = 0; mt < 2; mt++){
            #pragma unroll
            for (int nt = 0; nt < 2; nt++){
                const int n  = n0 + wn + 16*nt + l16;
                const int ob = o0 + wo + 16*mt + quad*4;
                #pragma unroll
                for (int rr = 0; rr < 4; rr++){
                    const int o = ob + rr;
                    float v = acc[mt][nt][rr] + j.Bp[o];
                    if (flags & CF_BN)   v = v*(bninv*bng[o]) + bnb[o];
                    if (flags & CF_RELU) v = fmaxf(v, 0.f);
                    if (resb) v += resb[(size_t)o*256 + n];
                    const size_t oi = (size_t)o*256 + n;
                    if (of32) of32[oi] = v;
                    if (osH){
                        unsigned short hi = bf16_rn(v);
                        osH[oi] = hi;
                        osH[SBIG + oi] = bf16_rn(v - bf16_to_f(hi));
                    }
                }
            }
        }
    }
}

// ---------- sscm attention weights ----------
__global__ __launch_bounds__(64) void k_sscm_attn(SAJobs jo)
{
    const int br = blockIdx.y;
    const int h = blockIdx.x >> 3, b = blockIdx.x & 7, c = threadIdx.x;
    const int ci = c*8 + h;
    float qc = jo.q8[br][b*512 + ci];
    float s[8];
    #pragma unroll
    for (int d = 0; d < 8; d++){
        float p = qc * jo.k8[br][d*512 + ci];
        p = wave_sum(p);
        s[d] = p * 0.125f;
    }
    float m = s[0];
    #pragma unroll
    for (int d = 1; d < 8; d++) m = fmaxf(m, s[d]);
    float sum = 0.f;
    #pragma unroll
    for (int d = 0; d < 8; d++){ s[d] = __expf(s[d]-m); sum += s[d]; }
    float r = 1.f/sum;
    if (c < 8){
        float v = s[0];
        #pragma unroll
        for (int d = 1; d < 8; d++) if (c == d) v = s[d];
        jo.aw[br][blockIdx.x*8 + c] = v*r;
    }
}

// ---------- sscm apply: fp32 v in pool, split output (feeds pa conv only) ----------
__global__ __launch_bounds__(256) void k_sscm_apply(SPJobs jo)
{
    const int br = blockIdx.y;
    const int idx = blockIdx.x*256 + threadIdx.x;
    const int pix = idx & 255, e = (idx >> 8) & 511, b = idx >> 17;
    const int h = e & 7;
    const float* aw = jo.aw[br] + (h*8 + b)*8;
    const float* v = F32(OFF_FV + (size_t)br*TS);
    float acc = 0.f;
    #pragma unroll
    for (int d = 0; d < 8; d++) acc += aw[d] * v[(size_t)d*IMG + (size_t)e*256 + pix];
    unsigned short* H = SPL(OFF_AP + (size_t)br*TS);
    unsigned short hi = bf16_rn(acc);
    H[idx] = hi;
    H[SBIG + idx] = bf16_rn(acc - bf16_to_f(hi));
}

// ---------- pixel cross-batch attention v5: pre-split Q/K/V, pure-copy staging ----------
__global__ __launch_bounds__(256) void k_pixel_mfma()
{
    __shared__ char smem[61440];
    unsigned short* sQh = (unsigned short*)smem;      // [2 ks][64 q][40]
    unsigned short* sQl = sQh + 2*64*40;
    unsigned short* sKh = sQl + 2*64*40;              // [2 ks][128 m][40]
    unsigned short* sKl = sKh + 2*128*40;
    unsigned short* sP  = (unsigned short*)smem;      // [4 ks][64 q][40]
    unsigned short* sVh = sP  + 4*64*40;              // [4 ks][64 c][40]
    unsigned short* sVl = sVh + 4*64*40;

    const int br = blockIdx.y >> 3, b = blockIdx.y & 7;
    const unsigned short* Qs = SPL(OFF_PQ + (size_t)br*TS);
    const unsigned short* Ks = SPL(OFF_PK + (size_t)br*TS);
    const unsigned short* Vs = SPL(OFF_PV + (size_t)br*TS);
    float* O = F32(OFF_FO + (size_t)br*TS);

    const int nt = blockIdx.x & 3, d = blockIdx.x >> 2;
    const int h = blockIdx.z;
    const int tid = threadIdx.x;
    const int wv = tid >> 6, lane = tid & 63;
    const int quad = lane >> 4, l16 = lane & 15;
    const int n0 = nt * 64;
    const size_t bQ = (size_t)b * IMG;
    const size_t bK = (size_t)d * IMG;

    {   // stage Q tile (pure copy)
        const int q = tid & 63, c0 = tid >> 6;
        #pragma unroll
        for (int r = 0; r < 16; r++){
            int c = c0 + 4*r;
            size_t gi = bQ + (size_t)(c*8+h)*256 + n0 + q;
            int idx = (c>>5)*2560 + q*40 + (c&31);
            sQh[idx] = Qs[gi];
            sQl[idx] = Qs[SBIG + gi];
        }
    }
    {   // stage K half 0
        const int mloc = tid & 127, cb0 = tid >> 7;
        #pragma unroll
        for (int p = 0; p < 4; p++){
            int cb = cb0 + 2*p;
            short8 hi8, lo8;
            #pragma unroll
            for (int j = 0; j < 8; j++){
                size_t gi = bK + (size_t)((cb*8+j)*8+h)*256 + mloc;
                hi8[j] = (short)Ks[gi];
                lo8[j] = (short)Ks[SBIG + gi];
            }
            int idx = (cb>>2)*5120 + mloc*40 + (cb&3)*8;
            *(short8*)&sKh[idx] = hi8;
            *(short8*)&sKl[idx] = lo8;
        }
    }
    __syncthreads();

    short8 bqh[2], bql[2];
    #pragma unroll
    for (int ks = 0; ks < 2; ks++){
        int idx = ks*2560 + (wv*16 + l16)*40 + quad*8;
        bqh[ks] = *(const short8*)&sQh[idx];
        bql[ks] = *(const short8*)&sQl[idx];
    }

    f32x4 S[16] = {};
    #pragma unroll
    for (int hm = 0; hm < 2; hm++){
        if (hm == 1){
            __syncthreads();
            const int mloc = tid & 127, cb0 = tid >> 7;
            #pragma unroll
            for (int p = 0; p < 4; p++){
                int cb = cb0 + 2*p;
                short8 hi8, lo8;
                #pragma unroll
                for (int j = 0; j < 8; j++){
                    size_t gi = bK + (size_t)((cb*8+j)*8+h)*256 + 128 + mloc;
                    hi8[j] = (short)Ks[gi];
                    lo8[j] = (short)Ks[SBIG + gi];
                }
                int idx = (cb>>2)*5120 + mloc*40 + (cb&3)*8;
                *(short8*)&sKh[idx] = hi8;
                *(short8*)&sKl[idx] = lo8;
            }
            __syncthreads();
        }
        #pragma unroll
        for (int mtl = 0; mtl < 8; mtl++){
            #pragma unroll
            for (int ks = 0; ks < 2; ks++){
                int idx = ks*5120 + (mtl*16 + l16)*40 + quad*8;
                short8 ah = *(const short8*)&sKh[idx];
                short8 al = *(const short8*)&sKl[idx];
                S[hm*8+mtl] = __builtin_amdgcn_mfma_f32_16x16x32_bf16(ah, bqh[ks], S[hm*8+mtl], 0, 0, 0);
                S[hm*8+mtl] = __builtin_amdgcn_mfma_f32_16x16x32_bf16(ah, bql[ks], S[hm*8+mtl], 0, 0, 0);
                S[hm*8+mtl] = __builtin_amdgcn_mfma_f32_16x16x32_bf16(al, bqh[ks], S[hm*8+mtl], 0, 0, 0);
            }
        }
    }

    {   // softmax over all 256 m per q-column (NO scale -- matches source)
        float mx = -3.4e38f;
        #pragma unroll
        for (int t = 0; t < 16; t++)
            #pragma unroll
            for (int r = 0; r < 4; r++) mx = fmaxf(mx, S[t][r]);
        mx = fmaxf(mx, __shfl_xor(mx, 16));
        mx = fmaxf(mx, __shfl_xor(mx, 32));
        float sum = 0.f;
        #pragma unroll
        for (int t = 0; t < 16; t++)
            #pragma unroll
            for (int r = 0; r < 4; r++){ S[t][r] = __expf(S[t][r]-mx); sum += S[t][r]; }
        sum += __shfl_xor(sum, 16);
        sum += __shfl_xor(sum, 32);
        float rr = 1.f/sum;
        #pragma unroll
        for (int t = 0; t < 16; t++)
            #pragma unroll
            for (int r = 0; r < 4; r++) S[t][r] *= rr;
    }
    __syncthreads();

    f32x4 oac[4] = {};
    #pragma unroll
    for (int hm = 0; hm < 2; hm++){
        #pragma unroll
        for (int mtl = 0; mtl < 8; mtl++){
            short4v p4;
            #pragma unroll
            for (int r = 0; r < 4; r++) p4[r] = (short)bf16_rn(S[hm*8+mtl][r]);
            int idx = (mtl>>1)*2560 + (wv*16 + l16)*40 + 16*(mtl&1) + quad*4;
            *(short4v*)&sP[idx] = p4;
        }
        {   // stage V half (pure 4B copies)
            const int mp = tid & 63, c0 = tid >> 6;
            #pragma unroll
            for (int p = 0; p < 16; p++){
                int c = c0 + 4*p;
                size_t gi = bK + (size_t)(c*8+h)*256 + hm*128 + 2*mp;
                int idx = (mp>>4)*2560 + c*40 + ((2*mp)&31);
                *(unsigned*)&sVh[idx] = *(const unsigned*)&Vs[gi];
                *(unsigned*)&sVl[idx] = *(const unsigned*)&Vs[SBIG + gi];
            }
        }
        __syncthreads();
        #pragma unroll
        for (int ks = 0; ks < 4; ks++){
            int pidx = ks*2560 + (wv*16 + l16)*40 + quad*8;
            short8 bp = *(const short8*)&sP[pidx];
            #pragma unroll
            for (int ct = 0; ct < 4; ct++){
                int vidx = ks*2560 + (ct*16 + l16)*40 + quad*8;
                short8 vh = *(const short8*)&sVh[vidx];
                short8 vl = *(const short8*)&sVl[vidx];
                oac[ct] = __builtin_amdgcn_mfma_f32_16x16x32_bf16(vh, bp, oac[ct], 0, 0, 0);
                oac[ct] = __builtin_amdgcn_mfma_f32_16x16x32_bf16(vl, bp, oac[ct], 0, 0, 0);
            }
        }
        __syncthreads();
    }

    const int q = n0 + wv*16 + l16;
    #pragma unroll
    for (int ct = 0; ct < 4; ct++){
        #pragma unroll
        for (int r = 0; r < 4; r++){
            int c = ct*16 + quad*4 + r;
            unsafeAtomicAdd(&O[bQ + (size_t)(c*8+h)*256 + q], oac[ct][r]);
        }
    }
}

// ---------- LN over channels -> split output (feeds lin conv only) ----------
__global__ __launch_bounds__(64) void k_ln_pix(PixLnJobs jo,
    const float* __restrict__ g, const float* __restrict__ be)
{
    const int br = blockIdx.y;
    const int bn = blockIdx.x;
    const int b = bn >> 8, n = bn & 255;
    const int lane = threadIdx.x;
    const float* p = jo.in[br] + (size_t)b*IMG + n;
    unsigned short* H = SPL(OFF_LN + (size_t)br*TS);
    float v[8]; float s = 0.f;
    #pragma unroll
    for (int i = 0; i < 8; i++){ v[i] = p[(size_t)(lane + 64*i)*256]; s += v[i]; }
    s = wave_sum(s);
    float mean = s * (1.f/512.f);
    float q = 0.f;
    #pragma unroll
    for (int i = 0; i < 8; i++){ float d = v[i]-mean; q += d*d; }
    q = wave_sum(q);
    float rstd = rsqrtf(q*(1.f/512.f) + 1e-5f);
    #pragma unroll
    for (int i = 0; i < 8; i++){
        int c = lane + 64*i;
        float val = (v[i]-mean)*rstd*g[c] + be[c];
        size_t oi = (size_t)b*IMG + (size_t)c*256 + n;
        unsigned short hi = bf16_rn(val);
        H[oi] = hi;
        H[SBIG + oi] = bf16_rn(val - bf16_to_f(hi));
    }
}

// ---------- host orchestration ----------
extern "C" void kernel_launch(void* const* d_in, const int* in_sizes, int n_in,
                              void* d_out, int out_size, void* d_ws, size_t ws_size,
                              hipStream_t stream)
{
    const float* xs    = (const float*)d_in[0];
    const float* xq    = (const float*)d_in[1];
    const float* qkvw  = (const float*)d_in[2];  const float* qkvb = (const float*)d_in[3];
    const float* paw   = (const float*)d_in[4];  const float* pab  = (const float*)d_in[5];
    const float* ln1g  = (const float*)d_in[6];  const float* ln1b = (const float*)d_in[7];
    const float* f1w   = (const float*)d_in[8];  const float* f1b  = (const float*)d_in[9];
    const float* f2w   = (const float*)d_in[10]; const float* f2b  = (const float*)d_in[11];
    const float* ln2g  = (const float*)d_in[12]; const float* ln2b = (const float*)d_in[13];
    const float* c1w   = (const float*)d_in[14]; const float* c1b  = (const float*)d_in[15];
    const float* c2w   = (const float*)d_in[16]; const float* c2b  = (const float*)d_in[17];
    const float* bng   = (const float*)d_in[18]; const float* bnb  = (const float*)d_in[19];
    const float* caqw  = (const float*)d_in[20]; const float* caqb = (const float*)d_in[21];
    const float* cakw  = (const float*)d_in[22]; const float* cakb = (const float*)d_in[23];
    const float* cavw  = (const float*)d_in[24]; const float* cavb = (const float*)d_in[25];
    const float* capw  = (const float*)d_in[26]; const float* capb = (const float*)d_in[27];
    const float* pqw   = (const float*)d_in[28]; const float* pqb  = (const float*)d_in[29];
    const float* pkw   = (const float*)d_in[30]; const float* pkb  = (const float*)d_in[31];
    const float* pvw   = (const float*)d_in[32]; const float* pvb  = (const float*)d_in[33];
    const float* ppw   = (const float*)d_in[34]; const float* ppb  = (const float*)d_in[35];
    const float* plng  = (const float*)d_in[36]; const float* plnb = (const float*)d_in[37];
    const float* plinw = (const float*)d_in[38]; const float* plinb= (const float*)d_in[39];

    // small ws scratch (fp32), 2 branch regions
    float* smb = (float*)d_ws;
    auto SM = [&](int br){ return smb + (size_t)br*131072; };
    auto GAP=[&](int br){ return SM(br); };            auto QKV=[&](int br){ return SM(br)+4096; };
    auto OM =[&](int br){ return SM(br)+20480; };      auto AA =[&](int br){ return SM(br)+24576; };
    auto HB =[&](int br){ return SM(br)+28672; };      auto A2 =[&](int br){ return SM(br)+32768; };
    auto LNB=[&](int br){ return SM(br)+36864; };      auto S8 =[&](int br){ return SM(br)+40960; };
    auto ATW=[&](int br){ return SM(br)+106496; };     auto Q8 =[&](int br){ return SM(br)+107008; };
    auto K8 =[&](int br){ return SM(br)+111104; };

    const float bninv = 1.0f / sqrtf(1.0f + 1e-5f);
    float* out0 = (float*)d_out;
    float* out1 = out0 + (size_t)BIGF;

    // weight pre-split (widx: 0=c2 1=cav 2=cap 3=pq 4=pk 5=pv 6=pp 7=plin)
    W8 w8 = {{c2w, cavw, capw, pqw, pkw, pvw, ppw, plinw}};
    k_splitw<<<dim3(256,8), 256, 0, stream>>>(w8);

    // ================= ASRI (paired) =================
    {
        GapJobs gj = {{xs, xq}, {0,0}, {GAP(0), GAP(1)}};
        k_gap<<<dim3(4096,2), 64, 0, stream>>>(gj);
        G8Jobs qj = {{{GAP(0), qkvw, qkvb, nullptr, QKV(0)}, {GAP(1), qkvw, qkvb, nullptr, QKV(1)}}};
        k_gemm8<<<dim3(2048,2), 64, 0, stream>>>(qj, 0, 0, 2048, 0);
        AAJobs aj = {{QKV(0), QKV(1)}, {OM(0), OM(1)}};
        k_asri_attn<<<dim3(64,2), 64, 0, stream>>>(aj);
        G8Jobs pj = {{{OM(0), paw, pab, QKV(0), AA(0)}, {OM(1), paw, pab, QKV(1), AA(1)}}};
        k_gemm8<<<dim3(512,2), 64, 0, stream>>>(pj, 1536, 2048, 512, 0);
        LnJobs l1 = {{AA(0), AA(1)}, {LNB(0), LNB(1)}};
        k_ln8<<<dim3(8,2), 64, 0, stream>>>(l1, ln1g, ln1b);
        G8Jobs fj = {{{LNB(0), f1w, f1b, nullptr, HB(0)}, {LNB(1), f1w, f1b, nullptr, HB(1)}}};
        k_gemm8<<<dim3(512,2), 64, 0, stream>>>(fj, 0, 0, 512, 1);
        G8Jobs f2j = {{{HB(0), f2w, f2b, AA(0), A2(0)}, {HB(1), f2w, f2b, AA(1), A2(1)}}};
        k_gemm8<<<dim3(512,2), 64, 0, stream>>>(f2j, 0, 512, 512, 0);
        LnJobs l2 = {{A2(0), A2(1)}, {LNB(0), LNB(1)}};
        k_ln8<<<dim3(8,2), 64, 0, stream>>>(l2, ln2g, ln2b);
        G8Jobs cj = {{{LNB(0), c1w, c1b, nullptr, S8(0)}, {LNB(1), c1w, c1b, nullptr, S8(1)}}};
        k_gemm8<<<dim3(8192,2), 64, 0, stream>>>(cj, 0, 0, 8192, 0);
        UpJobs uj = {{S8(0), S8(1)}};
        k_up<<<dim3(4096,2), 256, 0, stream>>>(uj);
        ConvJobs c2j = {};
        c2j.j[0] = {OFF_UP + 0*TS, OFF_FSA + 0*TS, OFF_SAS + 0*TS, 0, xs, nullptr, c2b, 0,
                    CF_BN|CF_RELU|CF_RESE|CF_OF32P|CF_OSPL};
        c2j.j[1] = {OFF_UP + 1*TS, OFF_FSA + 1*TS, OFF_SAS + 1*TS, 0, xq, nullptr, c2b, 0,
                    CF_BN|CF_RELU|CF_RESE|CF_OF32P|CF_OSPL};
        k_convm<<<dim3(4,8,16), 512, 0, stream>>>(c2j, bng, bnb, bninv);
    }

    // ================= SSCM (paired) =================
    {
        GapJobs gj = {{nullptr, nullptr}, {OFF_FSA + 0*TS, OFF_FSA + 1*TS}, {GAP(0), GAP(1)}};
        k_gap<<<dim3(4096,2), 64, 0, stream>>>(gj);
        G8Jobs qj = {{{GAP(0), caqw, caqb, nullptr, Q8(0)},
                      {GAP(1), cakw, cakb, nullptr, K8(0)},
                      {GAP(1), caqw, caqb, nullptr, Q8(1)},
                      {GAP(0), cakw, cakb, nullptr, K8(1)}}};
        k_gemm8<<<dim3(512,4), 64, 0, stream>>>(qj, 0, 0, 512, 0);
        SAJobs sj = {{Q8(0), Q8(1)}, {K8(0), K8(1)}, {ATW(0), ATW(1)}};
        k_sscm_attn<<<dim3(64,2), 64, 0, stream>>>(sj);
        ConvJobs vj = {};
        vj.j[0] = {OFF_SAS + 1*TS, OFF_FV + 0*TS, 0, 0, nullptr, nullptr, cavb, 1, CF_OF32P};
        vj.j[1] = {OFF_SAS + 0*TS, OFF_FV + 1*TS, 0, 0, nullptr, nullptr, cavb, 1, CF_OF32P};
        k_convm<<<dim3(4,8,16), 512, 0, stream>>>(vj, bng, bnb, 1.f);
        SPJobs pj = {{ATW(0), ATW(1)}};
        k_sscm_apply<<<dim3(4096,2), 256, 0, stream>>>(pj);
        ConvJobs aj = {};
        aj.j[0] = {OFF_AP + 0*TS, 0, OFF_CA + 0*TS, 0, nullptr, nullptr, capb, 2, CF_RELU|CF_OSPL};
        aj.j[1] = {OFF_AP + 1*TS, 0, OFF_CA + 1*TS, 0, nullptr, nullptr, capb, 2, CF_RELU|CF_OSPL};
        k_convm<<<dim3(4,8,16), 512, 0, stream>>>(aj, bng, bnb, 1.f);
    }

    // ================= PIXEL (paired) =================
    {
        // br0: x1=sa_s (SAS0), x2=ca_q (CA1); br1: x1=sa_q (SAS1), x2=ca_s (CA0)
        ConvJobs qkvj = {};
        qkvj.j[0] = {OFF_SAS + 0*TS, 0, OFF_PQ + 0*TS, 0, nullptr, nullptr, pqb, 3, CF_OSPL};
        qkvj.j[1] = {OFF_CA  + 1*TS, 0, OFF_PK + 0*TS, 0, nullptr, nullptr, pkb, 4, CF_OSPL};
        qkvj.j[2] = {OFF_CA  + 1*TS, 0, OFF_PV + 0*TS, 0, nullptr, nullptr, pvb, 5, CF_OSPL};
        qkvj.j[3] = {OFF_SAS + 1*TS, 0, OFF_PQ + 1*TS, 0, nullptr, nullptr, pqb, 3, CF_OSPL};
        qkvj.j[4] = {OFF_CA  + 0*TS, 0, OFF_PK + 1*TS, 0, nullptr, nullptr, pkb, 4, CF_OSPL};
        qkvj.j[5] = {OFF_CA  + 0*TS, 0, OFF_PV + 1*TS, 0, nullptr, nullptr, pvb, 5, CF_OSPL};
        k_convm<<<dim3(4,8,48), 512, 0, stream>>>(qkvj, bng, bnb, 1.f);
        k_zero<<<dim3(1024,2), 256, 0, stream>>>();
        k_pixel_mfma<<<dim3(32,16,8), 256, 0, stream>>>();
        k_split_o<<<dim3(1024,2), 256, 0, stream>>>();
        ConvJobs ppj = {};
        ppj.j[0] = {OFF_OS + 0*TS, 0, 0, OFF_FSA + 0*TS, nullptr, out0, ppb, 6, CF_RESP|CF_OF32E};
        ppj.j[1] = {OFF_OS + 1*TS, 0, 0, OFF_FSA + 1*TS, nullptr, out1, ppb, 6, CF_RESP|CF_OF32E};
        k_convm<<<dim3(4,8,16), 512, 0, stream>>>(ppj, bng, bnb, 1.f);
        PixLnJobs lj = {{out0, out1}};
        k_ln_pix<<<dim3(2048,2), 64, 0, stream>>>(lj, plng, plnb);
        ConvJobs lnj = {};
        lnj.j[0] = {OFF_LN + 0*TS, 0, 0, 0, nullptr, out0, plinb, 7, CF_RELU|CF_OF32E};
        lnj.j[1] = {OFF_LN + 1*TS, 0, 0, 0, nullptr, out1, plinb, 7, CF_RELU|CF_OF32E};
        k_convm<<<dim3(4,8,16), 512, 0, stream>>>(lnj, bng, bnb, 1.f);
    }

    (void)in_sizes; (void)n_in; (void)out_size; (void)ws_size;
}